// Round 13
// baseline (188.049 us; speedup 1.0000x reference)
//
#include <hip/hip_runtime.h>
#include <hip/hip_fp16.h>
#include <stdint.h>

typedef __attribute__((ext_vector_type(4))) int int32x4;
typedef __attribute__((ext_vector_type(4))) float float32x4;

#define TOKENS 8192
#define IN_F   4096
#define OUT_F  4096
#define BM 256
#define BN 256
#define BK 128              // int8 per K-tile = 128 B rows
#define NT (IN_F / BK)      // 32 K-tiles
#define ESTR 260            // epilogue LDS row stride (f32): 2-way bank alias = free

#define AS1 __attribute__((address_space(1)))
#define AS3 __attribute__((address_space(3)))

// ------- fused pack: int32->int8 for x and w, plus bias tuple-output -------
__global__ __launch_bounds__(256)
void pack_all_kernel(const int* __restrict__ x32, const int* __restrict__ w32,
                     const float* __restrict__ bias,
                     uint32_t* __restrict__ x8, uint32_t* __restrict__ w8,
                     float* __restrict__ bias_out)
{
    const int gid = blockIdx.x * 256 + threadIdx.x;
    if (gid < OUT_F / 4) {
        float32x4 b4 = __builtin_nontemporal_load((const float32x4*)bias + gid);
        __builtin_nontemporal_store(b4, (float32x4*)bias_out + gid);
    }

    const int nx4 = TOKENS * IN_F / 4;
    const int nw4 = OUT_F * IN_F / 4;
    for (int i = gid; i < nx4 + nw4; i += gridDim.x * 256) {
        const int* s; uint32_t* d; int j;
        if (i < nx4) { s = x32; d = x8; j = i; }
        else         { s = w32; d = w8; j = i - nx4; }
        int32x4 v = __builtin_nontemporal_load((const int32x4*)s + j);
        d[j] = (uint32_t)(v[0] & 0xff) | ((uint32_t)(v[1] & 0xff) << 8) |
               ((uint32_t)(v[2] & 0xff) << 16) | ((uint32_t)v[3] << 24);
    }
}

// ---- 256x256 i8 GEMM: register-pipelined half-K steps --------------------
// 512 threads = 8 waves (4M x 2N). Each K-tile = 2 half-steps (ks=0/1).
// Per half-step: issue NEXT half-step's 12 ds_read_b128 into the spare frag
// set, then 32 MFMA reading ONLY registers (LDS reads complete underneath),
// then sched_barrier+lgkmcnt(0)+s_barrier. Staging (tile t+2, 8 gload_lds)
// issues in halfB, where halfA's lgkmcnt+barrier proves all tile-t reads done.
__global__ __launch_bounds__(512, 2)
void w8a8_gemm_kernel(const int8_t* __restrict__ x,
                      const int8_t* __restrict__ w,
                      const float* __restrict__ scale,
                      const float* __restrict__ bias,
                      float* __restrict__ out)
{
    __shared__ int8_t smem[131072];            // staging: lA | lB ; epilogue reuse
    int8_t* lA = smem;                         // [buf][half][128][128B] 64 KB
    int8_t* lB = smem + 65536;                 // 64 KB

    const int tid = threadIdx.x;
    const int wv  = tid >> 6;
    const int l   = tid & 63;
    const int wqm = wv >> 1;               // 0..3  (32-row strip within 128-row half)
    const int wqn = wv & 1;                // 0..1  (64-col strip within 128-col half)

    // XCD-chunked bijective swizzle (r10-proven): 512 blocks = 8 XCDs x (8bn x 8bm)
    const int xc  = blockIdx.x & 7;
    const int idx = blockIdx.x >> 3;
    const int bn  = (xc & 1) * 8 + (idx & 7);    // 0..15
    const int bm  = (xc >> 1) * 8 + (idx >> 3);  // 0..31

    const int8_t* baseA = x + (size_t)bm * BM * IN_F;
    const int8_t* baseB = w + (size_t)bn * BN * IN_F;

    // staging: T2 swizzle via pre-swizzled global source (rule 21)
    const int seg0 = wv * 2, seg1 = wv * 2 + 1;   // 16 segs x 8 rows per half
    const int r8   = l >> 3;
    const int swc  = (((l & 7) ^ r8) << 4);

    const int8_t* pA0 = baseA + (size_t)(seg0 * 8 + r8) * IN_F + swc;
    const int8_t* pA1 = baseA + (size_t)(seg1 * 8 + r8) * IN_F + swc;
    const int8_t* pB0 = baseB + (size_t)(seg0 * 8 + r8) * IN_F + swc;
    const int8_t* pB1 = baseB + (size_t)(seg1 * 8 + r8) * IN_F + swc;

    // fragment read addressing
    const int fr  = l & 15;
    const int xk  = (l & 7) << 4;
    const int cb0 = (l >> 4) << 4;

    int32x4 acc[2][2][2][4];
#pragma unroll
    for (int a0i = 0; a0i < 2; ++a0i)
#pragma unroll
        for (int a1i = 0; a1i < 2; ++a1i)
#pragma unroll
            for (int a2i = 0; a2i < 2; ++a2i)
#pragma unroll
                for (int a3i = 0; a3i < 4; ++a3i)
                    acc[a0i][a1i][a2i][a3i] = (int32x4){0, 0, 0, 0};

    // two register frag sets (static names — rule #20), 48 VGPR each
    int32x4 a0[2][2], b0[2][4];   // set 0
    int32x4 a1[2][2], b1[2][4];   // set 1

    // stage one half-tile: h4 = tile*4 + {0:A0 1:A1 2:B0 3:B1}
    auto stage_half = [&](int h4) {
        const int kt_ = h4 >> 2;
        const int wh_ = h4 & 3;
        const size_t off = (size_t)(wh_ & 1) * (128 * IN_F) + (size_t)kt_ * BK;
        const int8_t* s0 = ((wh_ < 2) ? pA0 : pB0) + off;
        const int8_t* s1 = ((wh_ < 2) ? pA1 : pB1) + off;
        int8_t* db = ((wh_ < 2) ? lA : lB) + ((kt_ & 1) << 15) + ((wh_ & 1) << 14);
        __builtin_amdgcn_global_load_lds(
            (const AS1 void*)s0, (AS3 void*)(db + seg0 * 1024), 16, 0, 0);
        __builtin_amdgcn_global_load_lds(
            (const AS1 void*)s1, (AS3 void*)(db + seg1 * 1024), 16, 0, 0);
    };
    auto stage_tile = [&](int tt) {
        stage_half(4 * tt + 0); stage_half(4 * tt + 1);
        stage_half(4 * tt + 2); stage_half(4 * tt + 3);
    };

#define LDFA(DST, LABP, KS)                                                            \
    do {                                                                               \
        _Pragma("unroll") for (int MH = 0; MH < 2; ++MH)                               \
        _Pragma("unroll") for (int mi = 0; mi < 2; ++mi)                               \
            DST[MH][mi] = *(const int32x4*)&(LABP)[(MH << 14) +                        \
                (wqm * 32 + mi * 16 + fr) * 128 + ((((KS) * 64) + cb0) ^ xk)];         \
    } while (0)

#define LDFB(DST, LBBP, KS)                                                            \
    do {                                                                               \
        _Pragma("unroll") for (int NH = 0; NH < 2; ++NH)                               \
        _Pragma("unroll") for (int ni = 0; ni < 4; ++ni)                               \
            DST[NH][ni] = *(const int32x4*)&(LBBP)[(NH << 14) +                        \
                (wqn * 64 + ni * 16 + fr) * 128 + ((((KS) * 64) + cb0) ^ xk)];         \
    } while (0)

#define MMA_ALL(AS_, BS_)                                                              \
    do {                                                                               \
        _Pragma("unroll") for (int MH = 0; MH < 2; ++MH)                               \
        _Pragma("unroll") for (int NH = 0; NH < 2; ++NH)                               \
        _Pragma("unroll") for (int mi = 0; mi < 2; ++mi)                               \
        _Pragma("unroll") for (int ni = 0; ni < 4; ++ni)                               \
            acc[MH][NH][mi][ni] = __builtin_amdgcn_mfma_i32_16x16x64_i8(               \
                AS_[MH][mi], BS_[NH][ni], acc[MH][NH][mi][ni], 0, 0, 0);               \
    } while (0)

    // ---- prologue: stage tiles 0 and 1; load tile0 ks0 into set0 ----
    stage_tile(0); stage_tile(1);
    asm volatile("s_waitcnt vmcnt(0)" ::: "memory");
    __builtin_amdgcn_s_barrier();
    LDFA(a0, lA, 0); LDFB(b0, lB, 0);   // compiler inserts the wait before first use

    // ---- main loop: 2 register-pipelined half-steps per K-tile ----
    for (int t = 0; t < NT; ++t) {
        const int8_t* curA = lA + ((t & 1) << 15);
        const int8_t* curB = lB + ((t & 1) << 15);
        const int8_t* othA = lA + (((t + 1) & 1) << 15);
        const int8_t* othB = lB + (((t + 1) & 1) << 15);

        // halfA: compute ks0 (set0), prefetch ks1 (set1) underneath
        LDFA(a1, curA, 1); LDFB(b1, curB, 1);       // 12 ds_read_b128
        __builtin_amdgcn_s_setprio(1);
        MMA_ALL(a0, b0);                            // 32 MFMA, register-only
        __builtin_amdgcn_s_setprio(0);
        __builtin_amdgcn_sched_barrier(0);
        asm volatile("s_waitcnt lgkmcnt(0)" ::: "memory");
        __builtin_amdgcn_s_barrier();               // all tile-t reads complete

        // halfB: compute ks1 (set1), prefetch tile t+1 ks0 (set0), stage t+2
        if (t + 1 < NT) { LDFA(a0, othA, 0); LDFB(b0, othB, 0); }
        if (t + 2 < NT) stage_tile(t + 2);          // -> parity t (safe after halfA barrier)
        __builtin_amdgcn_s_setprio(1);
        MMA_ALL(a1, b1);                            // 32 MFMA, register-only
        __builtin_amdgcn_s_setprio(0);
        __builtin_amdgcn_sched_barrier(0);
        asm volatile("s_waitcnt lgkmcnt(0)" ::: "memory");
        if (t + 2 < NT) asm volatile("s_waitcnt vmcnt(0)" ::: "memory");
        __builtin_amdgcn_s_barrier();
    }

    // ---- epilogue: LDS-staged, fully coalesced float4 nt stores (r8-verified) ----
    __syncthreads();
    int* eL = (int*)smem;
    const int c4   = tid & 63;          // float4 col index within 256-col block
    const int rowt = tid >> 6;          // 0..7
    const float32x4 sc4 = ((const float32x4*)scale)[bn * 64 + c4];
    const float32x4 bf4 = ((const float32x4*)bias )[bn * 64 + c4];
    const __half bh[4] = { __float2half(bf4[0]), __float2half(bf4[1]),
                           __float2half(bf4[2]), __float2half(bf4[3]) };
    const int r0 = (l >> 4) << 2;
    const int wr0 = (wqm & 1) * 32 + r0;

    for (int c = 0; c < 4; ++c) {
        if ((wqm >> 1) == (c & 1)) {
            const int MH = c >> 1;
#pragma unroll
            for (int NH = 0; NH < 2; ++NH)
#pragma unroll
                for (int mi = 0; mi < 2; ++mi)
#pragma unroll
                    for (int ni = 0; ni < 4; ++ni)
#pragma unroll
                        for (int r = 0; r < 4; ++r)
                            eL[(wr0 + mi * 16 + r) * ESTR +
                               NH * 128 + wqn * 64 + ni * 16 + fr] = acc[MH][NH][mi][ni][r];
        }
        __syncthreads();
#pragma unroll
        for (int p = 0; p < 8; ++p) {
            const int rl = p * 8 + rowt;
            int32x4 v = *(const int32x4*)&eL[rl * ESTR + c4 * 4];
            float32x4 o;
#pragma unroll
            for (int j = 0; j < 4; ++j) {
                __half h = __float2half((float)v[j] * sc4[j]);
                o[j] = __half2float(__hadd(h, bh[j]));
            }
            const size_t rowg = (size_t)(bm * 256 + c * 64 + rl);
            __builtin_nontemporal_store(o, (float32x4*)out + rowg * (OUT_F / 4) + bn * 64 + c4);
        }
        __syncthreads();   // copy-out done before next chunk overwrites
    }
#undef LDFA
#undef LDFB
#undef MMA_ALL
}

extern "C" void kernel_launch(void* const* d_in, const int* in_sizes, int n_in,
                              void* d_out, int out_size, void* d_ws, size_t ws_size,
                              hipStream_t stream)
{
    const int*   x32   = (const int*)d_in[0];
    const int*   w32   = (const int*)d_in[1];
    const float* scale = (const float*)d_in[2];
    const float* bias  = (const float*)d_in[3];
    float* out = (float*)d_out;

    int8_t* x8 = (int8_t*)d_ws;
    int8_t* w8 = x8 + (size_t)TOKENS * IN_F;

    pack_all_kernel<<<3072, 256, 0, stream>>>(x32, w32, bias, (uint32_t*)x8, (uint32_t*)w8,
                                              out + (size_t)TOKENS * OUT_F);

    w8a8_gemm_kernel<<<512, 512, 0, stream>>>(x8, w8, scale, bias, out);
}